// Round 1
// baseline (293.441 us; speedup 1.0000x reference)
//
#include <hip/hip_runtime.h>
#include <hip/hip_bf16.h>
#include <math.h>

#define DIM 256
#define NHEAD 8
#define HD 32
#define WH 5
#define WW 2
#define NTOK 10
#define WPAT 64
#define LTOK 5120
#define EPS 1e-5f

typedef __attribute__((ext_vector_type(8))) short bh8;
typedef __attribute__((ext_vector_type(4))) float fx4;

__device__ inline unsigned short f2bf(float f) {
    unsigned int u = __builtin_bit_cast(unsigned int, f);
    u += 0x7fffu + ((u >> 16) & 1u);
    return (unsigned short)(u >> 16);
}

__device__ inline float wave_reduce_sum(float v) {
    #pragma unroll
    for (int off = 32; off > 0; off >>= 1) v += __shfl_xor(v, off);
    return v;
}

// ---------------- kernel 0: weight prep (f32 [K][N] -> bf16 [N][K]) ----------------
__global__ void prep_kernel(const float* __restrict__ w1,
                            const float* __restrict__ w2,
                            unsigned short* __restrict__ wt) {
    int bid = blockIdx.x;            // 0..511
    int mat = bid >> 8;
    int n = bid & 255;
    const float* src = mat ? w2 : w1;
    unsigned short* dst = wt + mat * 65536 + n * 256;
    int k = threadIdx.x;
    dst[k] = f2bf(src[k * 256 + n]);
}

// ---------------- kernel 1: LN1 + window attention + residual -> x1 (in d_out) ------
__global__ __launch_bounds__(256) void attn_kernel(
    const float* __restrict__ x, const float* __restrict__ g1,
    const float* __restrict__ b1, const float* __restrict__ btab,
    float* __restrict__ x1) {
    __shared__ float xs[NTOK][DIM + 8];
    __shared__ float hs[NTOK][DIM + 8];
    __shared__ float pm[NHEAD * NTOK * NTOK];

    int w = blockIdx.x;              // 0..16383
    int b = w >> 9;
    int rh = (w >> 5) & 15;
    int cw = w & 31;
    int tid = threadIdx.x;
    int lane = tid & 63;
    int wave = tid >> 6;
    long base = (long)b * LTOK + rh * (WH * WPAT) + cw * WW;

    // stage window: 5 chunks of 512 contiguous floats (2 tokens each)
    #pragma unroll
    for (int i = 0; i < WH; ++i) {
        const float2* src = (const float2*)(x + (base + (long)i * WPAT) * DIM);
        float2 v = src[tid];
        int p = tid * 2;
        int tok = i * 2 + (p >> 8);
        int c = p & 255;
        *(float2*)&xs[tok][c] = v;
    }
    __syncthreads();

    // LN1: each wave handles tokens wave, wave+4, wave+8
    float4 g4 = *(const float4*)(g1 + lane * 4);
    float4 b4 = *(const float4*)(b1 + lane * 4);
    for (int tok = wave; tok < NTOK; tok += 4) {
        float4 v = *(const float4*)&xs[tok][lane * 4];
        float s = v.x + v.y + v.z + v.w;
        float q = v.x * v.x + v.y * v.y + v.z * v.z + v.w * v.w;
        s = wave_reduce_sum(s);
        q = wave_reduce_sum(q);
        float mean = s * (1.0f / DIM);
        float var = q * (1.0f / DIM) - mean * mean;
        float rstd = rsqrtf(var + EPS);
        float4 h;
        h.x = (v.x - mean) * rstd * g4.x + b4.x;
        h.y = (v.y - mean) * rstd * g4.y + b4.y;
        h.z = (v.z - mean) * rstd * g4.z + b4.z;
        h.w = (v.w - mean) * rstd * g4.w + b4.w;
        *(float4*)&hs[tok][lane * 4] = h;
    }
    __syncthreads();

    // logits: 8 heads x 10q x 10k dot-32 products + relative bias
    const float scale = 0.17677669529663689f;   // 32^-0.5
    for (int item = tid; item < NHEAD * NTOK * NTOK; item += 256) {
        int head = item / 100;
        int rem = item - head * 100;
        int q = rem / 10;
        int k = rem - q * 10;
        float acc = 0.f;
        #pragma unroll
        for (int d = 0; d < HD; ++d)
            acc += hs[q][head * HD + d] * hs[k][head * HD + d];
        int iq = q >> 1, jq = q & 1, ik = k >> 1, jk = k & 1;
        int bidx = (iq - ik + WH - 1) * (2 * WW - 1) + (jq - jk + WW - 1);
        pm[item] = acc * scale + btab[bidx * NHEAD + head];
    }
    __syncthreads();

    // softmax: 80 rows of 10
    if (tid < NHEAD * NTOK) {
        float* row = pm + tid * NTOK;
        float m = row[0];
        #pragma unroll
        for (int k = 1; k < NTOK; ++k) m = fmaxf(m, row[k]);
        float e[NTOK];
        float s = 0.f;
        #pragma unroll
        for (int k = 0; k < NTOK; ++k) { e[k] = __expf(row[k] - m); s += e[k]; }
        float inv = 1.0f / s;
        #pragma unroll
        for (int k = 0; k < NTOK; ++k) row[k] = e[k] * inv;
    }
    __syncthreads();

    // PV + residual; thread = channel
    int head = tid >> 5;
    float hv[NTOK];
    #pragma unroll
    for (int k = 0; k < NTOK; ++k) hv[k] = hs[k][tid];
    #pragma unroll
    for (int q = 0; q < NTOK; ++q) {
        const float* pr = pm + (head * NTOK + q) * NTOK;
        float acc = 0.f;
        #pragma unroll
        for (int k = 0; k < NTOK; ++k) acc += pr[k] * hv[k];
        float o = xs[q][tid] + acc;
        long l = base + (q >> 1) * WPAT + (q & 1);
        x1[l * DIM + tid] = o;
    }
}

// ---------------- kernel 2: LN2 + MLP (bf16 MFMA) + residual, in-place on d_out -----
__global__ __launch_bounds__(256) void mlp_kernel(
    float* __restrict__ xio,
    const float* __restrict__ g2, const float* __restrict__ b2,
    const unsigned short* __restrict__ wt,
    const float* __restrict__ mb1, const float* __restrict__ mb2) {
    __shared__ unsigned short As[64][DIM + 8];

    int m0 = blockIdx.x * 64;
    int tid = threadIdx.x;
    int lane = tid & 63;
    int wave = tid >> 6;
    int lr = lane & 15;   // row/col within 16
    int lk = lane >> 4;   // 0..3 (k-group / acc row group)

    // LN2 -> bf16 into LDS
    float4 g4 = *(const float4*)(g2 + lane * 4);
    float4 b4 = *(const float4*)(b2 + lane * 4);
    for (int tok = wave; tok < 64; tok += 4) {
        const float4 v = *(const float4*)(xio + (long)(m0 + tok) * DIM + lane * 4);
        float s = v.x + v.y + v.z + v.w;
        float q = v.x * v.x + v.y * v.y + v.z * v.z + v.w * v.w;
        s = wave_reduce_sum(s);
        q = wave_reduce_sum(q);
        float mean = s * (1.0f / DIM);
        float var = q * (1.0f / DIM) - mean * mean;
        float rstd = rsqrtf(var + EPS);
        unsigned short h0 = f2bf((v.x - mean) * rstd * g4.x + b4.x);
        unsigned short h1 = f2bf((v.y - mean) * rstd * g4.y + b4.y);
        unsigned short h2 = f2bf((v.z - mean) * rstd * g4.z + b4.z);
        unsigned short h3 = f2bf((v.w - mean) * rstd * g4.w + b4.w);
        unsigned short* p = &As[tok][lane * 4];
        p[0] = h0; p[1] = h1; p[2] = h2; p[3] = h3;
    }
    __syncthreads();

    int n0 = wave * 64;
    const fx4 zero = {0.f, 0.f, 0.f, 0.f};

    // GEMM1: h1 = As @ W1  (W1 stored transposed bf16 [n][k])
    fx4 acc[4][4];
    #pragma unroll
    for (int mi = 0; mi < 4; ++mi)
        #pragma unroll
        for (int ni = 0; ni < 4; ++ni) acc[mi][ni] = zero;

    #pragma unroll
    for (int ko = 0; ko < 8; ++ko) {
        bh8 a[4], bf[4];
        #pragma unroll
        for (int mi = 0; mi < 4; ++mi)
            a[mi] = *(const bh8*)&As[mi * 16 + lr][ko * 32 + lk * 8];
        #pragma unroll
        for (int ni = 0; ni < 4; ++ni)
            bf[ni] = *(const bh8*)&wt[(n0 + ni * 16 + lr) * 256 + ko * 32 + lk * 8];
        #pragma unroll
        for (int mi = 0; mi < 4; ++mi)
            #pragma unroll
            for (int ni = 0; ni < 4; ++ni)
                acc[mi][ni] = __builtin_amdgcn_mfma_f32_16x16x32_bf16(a[mi], bf[ni], acc[mi][ni], 0, 0, 0);
    }
    __syncthreads();

    // bias1 + exact gelu -> bf16 back into As
    float bias1v[4];
    #pragma unroll
    for (int ni = 0; ni < 4; ++ni) bias1v[ni] = mb1[n0 + ni * 16 + lr];
    #pragma unroll
    for (int mi = 0; mi < 4; ++mi)
        #pragma unroll
        for (int ni = 0; ni < 4; ++ni)
            #pragma unroll
            for (int r = 0; r < 4; ++r) {
                float v = acc[mi][ni][r] + bias1v[ni];
                v = 0.5f * v * (1.0f + erff(v * 0.70710678118654752f));
                As[mi * 16 + lk * 4 + r][n0 + ni * 16 + lr] = f2bf(v);
            }
    __syncthreads();

    // GEMM2: h2 = h1 @ W2
    fx4 acc2[4][4];
    #pragma unroll
    for (int mi = 0; mi < 4; ++mi)
        #pragma unroll
        for (int ni = 0; ni < 4; ++ni) acc2[mi][ni] = zero;

    const unsigned short* w2t = wt + 65536;
    #pragma unroll
    for (int ko = 0; ko < 8; ++ko) {
        bh8 a[4], bf[4];
        #pragma unroll
        for (int mi = 0; mi < 4; ++mi)
            a[mi] = *(const bh8*)&As[mi * 16 + lr][ko * 32 + lk * 8];
        #pragma unroll
        for (int ni = 0; ni < 4; ++ni)
            bf[ni] = *(const bh8*)&w2t[(n0 + ni * 16 + lr) * 256 + ko * 32 + lk * 8];
        #pragma unroll
        for (int mi = 0; mi < 4; ++mi)
            #pragma unroll
            for (int ni = 0; ni < 4; ++ni)
                acc2[mi][ni] = __builtin_amdgcn_mfma_f32_16x16x32_bf16(a[mi], bf[ni], acc2[mi][ni], 0, 0, 0);
    }

    // bias2 + residual, in-place store
    float bias2v[4];
    #pragma unroll
    for (int ni = 0; ni < 4; ++ni) bias2v[ni] = mb2[n0 + ni * 16 + lr];
    #pragma unroll
    for (int mi = 0; mi < 4; ++mi)
        #pragma unroll
        for (int ni = 0; ni < 4; ++ni)
            #pragma unroll
            for (int r = 0; r < 4; ++r) {
                long row = m0 + mi * 16 + lk * 4 + r;
                int col = n0 + ni * 16 + lr;
                long idx = row * DIM + col;
                xio[idx] = xio[idx] + acc2[mi][ni][r] + bias2v[ni];
            }
}

extern "C" void kernel_launch(void* const* d_in, const int* in_sizes, int n_in,
                              void* d_out, int out_size, void* d_ws, size_t ws_size,
                              hipStream_t stream) {
    const float* x    = (const float*)d_in[0];
    const float* g1   = (const float*)d_in[1];
    const float* b1   = (const float*)d_in[2];
    const float* btab = (const float*)d_in[3];
    const float* g2   = (const float*)d_in[6];
    const float* b2   = (const float*)d_in[7];
    const float* w1   = (const float*)d_in[8];
    const float* mb1  = (const float*)d_in[9];
    const float* w2   = (const float*)d_in[10];
    const float* mb2  = (const float*)d_in[11];
    float* out = (float*)d_out;
    unsigned short* wt = (unsigned short*)d_ws;

    prep_kernel<<<512, 256, 0, stream>>>(w1, w2, wt);
    attn_kernel<<<16384, 256, 0, stream>>>(x, g1, b1, btab, out);
    mlp_kernel<<<2560, 256, 0, stream>>>(out, g2, b2, wt, mb1, mb2);
}

// Round 2
// 277.048 us; speedup vs baseline: 1.0592x; 1.0592x over previous
//
#include <hip/hip_runtime.h>
#include <hip/hip_bf16.h>
#include <math.h>

#define DIM 256
#define NHEAD 8
#define HD 32
#define WH 5
#define WW 2
#define NTOK 10
#define WPAT 64
#define LTOK 5120
#define EPS 1e-5f

typedef __attribute__((ext_vector_type(8))) short bh8;
typedef __attribute__((ext_vector_type(4))) short sh4;
typedef __attribute__((ext_vector_type(4))) float fx4;

__device__ inline unsigned short f2bf(float f) {
    unsigned int u = __builtin_bit_cast(unsigned int, f);
    u += 0x7fffu + ((u >> 16) & 1u);
    return (unsigned short)(u >> 16);
}

__device__ inline float wave_reduce_sum(float v) {
    #pragma unroll
    for (int off = 32; off > 0; off >>= 1) v += __shfl_xor(v, off);
    return v;
}

// ---------------- kernel 0: weight prep (f32 [K][N] -> bf16 [N][K]) ----------------
__global__ void prep_kernel(const float* __restrict__ w1,
                            const float* __restrict__ w2,
                            unsigned short* __restrict__ wt) {
    int bid = blockIdx.x;            // 0..511
    int mat = bid >> 8;
    int n = bid & 255;
    const float* src = mat ? w2 : w1;
    unsigned short* dst = wt + mat * 65536 + n * 256;
    int k = threadIdx.x;
    dst[k] = f2bf(src[k * 256 + n]);
}

// ---------------- kernel 1: LN1 + window attention + residual -> x1 (in d_out) ------
__global__ __launch_bounds__(256) void attn_kernel(
    const float* __restrict__ x, const float* __restrict__ g1,
    const float* __restrict__ b1, const float* __restrict__ btab,
    float* __restrict__ x1) {
    __shared__ float xs[NTOK][DIM + 8];
    __shared__ float hs[NTOK][DIM + 8];
    __shared__ float pm[NHEAD * NTOK * NTOK];

    int w = blockIdx.x;              // 0..16383
    int b = w >> 9;
    int rh = (w >> 5) & 15;
    int cw = w & 31;
    int tid = threadIdx.x;
    int lane = tid & 63;
    int wave = tid >> 6;
    long base = (long)b * LTOK + rh * (WH * WPAT) + cw * WW;

    // stage window: 5 chunks of 512 contiguous floats (2 tokens each)
    #pragma unroll
    for (int i = 0; i < WH; ++i) {
        const float2* src = (const float2*)(x + (base + (long)i * WPAT) * DIM);
        float2 v = src[tid];
        int p = tid * 2;
        int tok = i * 2 + (p >> 8);
        int c = p & 255;
        *(float2*)&xs[tok][c] = v;
    }
    __syncthreads();

    // LN1: each wave handles tokens wave, wave+4, wave+8
    float4 g4 = *(const float4*)(g1 + lane * 4);
    float4 b4 = *(const float4*)(b1 + lane * 4);
    for (int tok = wave; tok < NTOK; tok += 4) {
        float4 v = *(const float4*)&xs[tok][lane * 4];
        float s = v.x + v.y + v.z + v.w;
        float q = v.x * v.x + v.y * v.y + v.z * v.z + v.w * v.w;
        s = wave_reduce_sum(s);
        q = wave_reduce_sum(q);
        float mean = s * (1.0f / DIM);
        float var = q * (1.0f / DIM) - mean * mean;
        float rstd = rsqrtf(var + EPS);
        float4 h;
        h.x = (v.x - mean) * rstd * g4.x + b4.x;
        h.y = (v.y - mean) * rstd * g4.y + b4.y;
        h.z = (v.z - mean) * rstd * g4.z + b4.z;
        h.w = (v.w - mean) * rstd * g4.w + b4.w;
        *(float4*)&hs[tok][lane * 4] = h;
    }
    __syncthreads();

    // logits: 8 heads x 10q x 10k dot-32 products + relative bias
    const float scale = 0.17677669529663689f;   // 32^-0.5
    for (int item = tid; item < NHEAD * NTOK * NTOK; item += 256) {
        int head = item / 100;
        int rem = item - head * 100;
        int q = rem / 10;
        int k = rem - q * 10;
        float acc = 0.f;
        #pragma unroll
        for (int d = 0; d < HD; ++d)
            acc += hs[q][head * HD + d] * hs[k][head * HD + d];
        int iq = q >> 1, jq = q & 1, ik = k >> 1, jk = k & 1;
        int bidx = (iq - ik + WH - 1) * (2 * WW - 1) + (jq - jk + WW - 1);
        pm[item] = acc * scale + btab[bidx * NHEAD + head];
    }
    __syncthreads();

    // softmax: 80 rows of 10
    if (tid < NHEAD * NTOK) {
        float* row = pm + tid * NTOK;
        float m = row[0];
        #pragma unroll
        for (int k = 1; k < NTOK; ++k) m = fmaxf(m, row[k]);
        float e[NTOK];
        float s = 0.f;
        #pragma unroll
        for (int k = 0; k < NTOK; ++k) { e[k] = __expf(row[k] - m); s += e[k]; }
        float inv = 1.0f / s;
        #pragma unroll
        for (int k = 0; k < NTOK; ++k) row[k] = e[k] * inv;
    }
    __syncthreads();

    // PV + residual; thread = channel
    int head = tid >> 5;
    float hv[NTOK];
    #pragma unroll
    for (int k = 0; k < NTOK; ++k) hv[k] = hs[k][tid];
    #pragma unroll
    for (int q = 0; q < NTOK; ++q) {
        const float* pr = pm + (head * NTOK + q) * NTOK;
        float acc = 0.f;
        #pragma unroll
        for (int k = 0; k < NTOK; ++k) acc += pr[k] * hv[k];
        float o = xs[q][tid] + acc;
        long l = base + (q >> 1) * WPAT + (q & 1);
        x1[l * DIM + tid] = o;
    }
}

// ---------------- kernel 2: LN2 + MLP (bf16 MFMA) + residual, in-place on d_out -----
__global__ __launch_bounds__(256) void mlp_kernel(
    float* __restrict__ xio,
    const float* __restrict__ g2, const float* __restrict__ b2,
    const unsigned short* __restrict__ wt,
    const float* __restrict__ mb1, const float* __restrict__ mb2) {
    __shared__ unsigned short As[64][DIM + 8];

    int m0 = blockIdx.x * 64;
    int tid = threadIdx.x;
    int lane = tid & 63;
    int wave = tid >> 6;
    int lr = lane & 15;   // row/col within 16
    int lk = lane >> 4;   // 0..3 (k-group / acc row group)
    int n0 = wave * 64;

    // ---- LN2 phase: bulk ILP loads. 4 threads per row, 16 independent float4 each.
    {
        int r = tid >> 2;          // 0..63
        int q = tid & 3;           // 0..3
        const float4* rowp = (const float4*)(xio + (long)(m0 + r) * DIM);
        float4 v[16];
        #pragma unroll
        for (int i = 0; i < 16; ++i) v[i] = rowp[q + 4 * i];

        float s = 0.f, sq = 0.f;
        #pragma unroll
        for (int i = 0; i < 16; ++i) {
            s += v[i].x + v[i].y + v[i].z + v[i].w;
            sq += v[i].x * v[i].x + v[i].y * v[i].y + v[i].z * v[i].z + v[i].w * v[i].w;
        }
        s += __shfl_xor(s, 1);  s += __shfl_xor(s, 2);
        sq += __shfl_xor(sq, 1); sq += __shfl_xor(sq, 2);
        float mean = s * (1.0f / DIM);
        float var = sq * (1.0f / DIM) - mean * mean;
        float rstd = rsqrtf(var + EPS);

        const float4* g4p = (const float4*)g2;
        const float4* b4p = (const float4*)b2;
        #pragma unroll
        for (int i = 0; i < 16; ++i) {
            int c4 = q + 4 * i;
            float4 gg = g4p[c4];
            float4 bb = b4p[c4];
            sh4 h;
            h.x = (short)f2bf((v[i].x - mean) * rstd * gg.x + bb.x);
            h.y = (short)f2bf((v[i].y - mean) * rstd * gg.y + bb.y);
            h.z = (short)f2bf((v[i].z - mean) * rstd * gg.z + bb.z);
            h.w = (short)f2bf((v[i].w - mean) * rstd * gg.w + bb.w);
            *(sh4*)&As[r][c4 * 4] = h;
        }
    }

    // prefetch GEMM1 ko=0 B-fragments before the barrier (overlap weight fetch)
    bh8 b1pre[4];
    #pragma unroll
    for (int ni = 0; ni < 4; ++ni)
        b1pre[ni] = *(const bh8*)&wt[(n0 + ni * 16 + lr) * 256 + lk * 8];
    __syncthreads();

    const fx4 zero = {0.f, 0.f, 0.f, 0.f};

    // ---- GEMM1: h1 = As @ W1  (W1 stored transposed bf16 [n][k])
    fx4 acc[4][4];
    #pragma unroll
    for (int mi = 0; mi < 4; ++mi)
        #pragma unroll
        for (int ni = 0; ni < 4; ++ni) acc[mi][ni] = zero;

    #pragma unroll
    for (int ko = 0; ko < 8; ++ko) {
        bh8 a[4], bf[4];
        #pragma unroll
        for (int mi = 0; mi < 4; ++mi)
            a[mi] = *(const bh8*)&As[mi * 16 + lr][ko * 32 + lk * 8];
        #pragma unroll
        for (int ni = 0; ni < 4; ++ni)
            bf[ni] = (ko == 0) ? b1pre[ni]
                   : *(const bh8*)&wt[(n0 + ni * 16 + lr) * 256 + ko * 32 + lk * 8];
        #pragma unroll
        for (int mi = 0; mi < 4; ++mi)
            #pragma unroll
            for (int ni = 0; ni < 4; ++ni)
                acc[mi][ni] = __builtin_amdgcn_mfma_f32_16x16x32_bf16(a[mi], bf[ni], acc[mi][ni], 0, 0, 0);
    }
    __syncthreads();

    // ---- bias1 + exact gelu -> bf16 back into As
    float bias1v[4];
    #pragma unroll
    for (int ni = 0; ni < 4; ++ni) bias1v[ni] = mb1[n0 + ni * 16 + lr];
    #pragma unroll
    for (int mi = 0; mi < 4; ++mi)
        #pragma unroll
        for (int ni = 0; ni < 4; ++ni)
            #pragma unroll
            for (int r = 0; r < 4; ++r) {
                float v = acc[mi][ni][r] + bias1v[ni];
                v = 0.5f * v * (1.0f + erff(v * 0.70710678118654752f));
                As[mi * 16 + lk * 4 + r][n0 + ni * 16 + lr] = f2bf(v);
            }

    // prefetch GEMM2 ko=0 B-fragments before the barrier
    const unsigned short* w2t = wt + 65536;
    bh8 b2pre[4];
    #pragma unroll
    for (int ni = 0; ni < 4; ++ni)
        b2pre[ni] = *(const bh8*)&w2t[(n0 + ni * 16 + lr) * 256 + lk * 8];
    __syncthreads();

    // ---- GEMM2: h2 = h1 @ W2
    fx4 acc2[4][4];
    #pragma unroll
    for (int mi = 0; mi < 4; ++mi)
        #pragma unroll
        for (int ni = 0; ni < 4; ++ni) acc2[mi][ni] = zero;

    #pragma unroll
    for (int ko = 0; ko < 8; ++ko) {
        bh8 a[4], bf[4];
        #pragma unroll
        for (int mi = 0; mi < 4; ++mi)
            a[mi] = *(const bh8*)&As[mi * 16 + lr][ko * 32 + lk * 8];
        #pragma unroll
        for (int ni = 0; ni < 4; ++ni)
            bf[ni] = (ko == 0) ? b2pre[ni]
                   : *(const bh8*)&w2t[(n0 + ni * 16 + lr) * 256 + ko * 32 + lk * 8];
        #pragma unroll
        for (int mi = 0; mi < 4; ++mi)
            #pragma unroll
            for (int ni = 0; ni < 4; ++ni)
                acc2[mi][ni] = __builtin_amdgcn_mfma_f32_16x16x32_bf16(a[mi], bf[ni], acc2[mi][ni], 0, 0, 0);
    }

    // ---- bias2 + residual, in-place store
    float bias2v[4];
    #pragma unroll
    for (int ni = 0; ni < 4; ++ni) bias2v[ni] = mb2[n0 + ni * 16 + lr];
    #pragma unroll
    for (int mi = 0; mi < 4; ++mi)
        #pragma unroll
        for (int ni = 0; ni < 4; ++ni)
            #pragma unroll
            for (int r = 0; r < 4; ++r) {
                long row = m0 + mi * 16 + lk * 4 + r;
                int col = n0 + ni * 16 + lr;
                long idx = row * DIM + col;
                xio[idx] = xio[idx] + acc2[mi][ni][r] + bias2v[ni];
            }
}

extern "C" void kernel_launch(void* const* d_in, const int* in_sizes, int n_in,
                              void* d_out, int out_size, void* d_ws, size_t ws_size,
                              hipStream_t stream) {
    const float* x    = (const float*)d_in[0];
    const float* g1   = (const float*)d_in[1];
    const float* b1   = (const float*)d_in[2];
    const float* btab = (const float*)d_in[3];
    const float* g2   = (const float*)d_in[6];
    const float* b2   = (const float*)d_in[7];
    const float* w1   = (const float*)d_in[8];
    const float* mb1  = (const float*)d_in[9];
    const float* w2   = (const float*)d_in[10];
    const float* mb2  = (const float*)d_in[11];
    float* out = (float*)d_out;
    unsigned short* wt = (unsigned short*)d_ws;

    prep_kernel<<<512, 256, 0, stream>>>(w1, w2, wt);
    attn_kernel<<<16384, 256, 0, stream>>>(x, g1, b1, btab, out);
    mlp_kernel<<<2560, 256, 0, stream>>>(out, g2, b2, wt, mb1, mb2);
}

// Round 3
// 202.484 us; speedup vs baseline: 1.4492x; 1.3682x over previous
//
#include <hip/hip_runtime.h>
#include <hip/hip_bf16.h>
#include <math.h>

#define DIM 256
#define NHEAD 8
#define HD 32
#define WH 5
#define WW 2
#define NTOK 10
#define WPAT 64
#define LTOK 5120
#define EPS 1e-5f

typedef __attribute__((ext_vector_type(8))) short bh8;
typedef __attribute__((ext_vector_type(4))) short sh4;
typedef __attribute__((ext_vector_type(4))) float fx4;

__device__ inline unsigned short f2bf(float f) {
    unsigned int u = __builtin_bit_cast(unsigned int, f);
    u += 0x7fffu + ((u >> 16) & 1u);
    return (unsigned short)(u >> 16);
}

__device__ inline float wave_reduce_sum(float v) {
    #pragma unroll
    for (int off = 32; off > 0; off >>= 1) v += __shfl_xor(v, off);
    return v;
}

// ---- kernel 0: weight prep. f32 [K][N] -> bf16 MFMA-fragment order:
//      wtf[((mat*4+s)*4+ni)*8+ko][lane][j] = W[ko*32+(lane>>4)*8+j][s*64+ni*16+(lane&15)]
//      so a wave's B-fragment load is one coalesced dwordx4 per (ni,ko).
__global__ void prep_kernel(const float* __restrict__ w1,
                            const float* __restrict__ w2,
                            unsigned short* __restrict__ wtf) {
    int gid = blockIdx.x * 256 + threadIdx.x;   // 16384 threads, 8 shorts each
    int lane = gid & 63;
    int ko = (gid >> 6) & 7;
    int ni = (gid >> 9) & 3;
    int s  = (gid >> 11) & 3;
    int mat = gid >> 13;
    const float* src = mat ? w2 : w1;
    int col = s * 64 + ni * 16 + (lane & 15);
    int k0 = ko * 32 + (lane >> 4) * 8;
    unsigned short* dst = wtf + (size_t)gid * 8;
    #pragma unroll
    for (int j = 0; j < 8; ++j)
        dst[j] = f2bf(src[(k0 + j) * 256 + col]);
}

// ---------------- kernel 1: LN1 + window attention + residual -> x1 (in d_out) ------
__global__ __launch_bounds__(256) void attn_kernel(
    const float* __restrict__ x, const float* __restrict__ g1,
    const float* __restrict__ b1, const float* __restrict__ btab,
    float* __restrict__ x1) {
    __shared__ float xs[NTOK][DIM + 8];
    __shared__ float hs[NTOK][DIM + 8];
    __shared__ float pm[NHEAD * NTOK * NTOK];

    int w = blockIdx.x;              // 0..16383
    int b = w >> 9;
    int rh = (w >> 5) & 15;
    int cw = w & 31;
    int tid = threadIdx.x;
    int lane = tid & 63;
    int wave = tid >> 6;
    long base = (long)b * LTOK + rh * (WH * WPAT) + cw * WW;

    #pragma unroll
    for (int i = 0; i < WH; ++i) {
        const float2* src = (const float2*)(x + (base + (long)i * WPAT) * DIM);
        float2 v = src[tid];
        int p = tid * 2;
        int tok = i * 2 + (p >> 8);
        int c = p & 255;
        *(float2*)&xs[tok][c] = v;
    }
    __syncthreads();

    float4 g4 = *(const float4*)(g1 + lane * 4);
    float4 b4 = *(const float4*)(b1 + lane * 4);
    for (int tok = wave; tok < NTOK; tok += 4) {
        float4 v = *(const float4*)&xs[tok][lane * 4];
        float s = v.x + v.y + v.z + v.w;
        float q = v.x * v.x + v.y * v.y + v.z * v.z + v.w * v.w;
        s = wave_reduce_sum(s);
        q = wave_reduce_sum(q);
        float mean = s * (1.0f / DIM);
        float var = q * (1.0f / DIM) - mean * mean;
        float rstd = rsqrtf(var + EPS);
        float4 h;
        h.x = (v.x - mean) * rstd * g4.x + b4.x;
        h.y = (v.y - mean) * rstd * g4.y + b4.y;
        h.z = (v.z - mean) * rstd * g4.z + b4.z;
        h.w = (v.w - mean) * rstd * g4.w + b4.w;
        *(float4*)&hs[tok][lane * 4] = h;
    }
    __syncthreads();

    const float scale = 0.17677669529663689f;   // 32^-0.5
    for (int item = tid; item < NHEAD * NTOK * NTOK; item += 256) {
        int head = item / 100;
        int rem = item - head * 100;
        int q = rem / 10;
        int k = rem - q * 10;
        float acc = 0.f;
        #pragma unroll
        for (int d = 0; d < HD; ++d)
            acc += hs[q][head * HD + d] * hs[k][head * HD + d];
        int iq = q >> 1, jq = q & 1, ik = k >> 1, jk = k & 1;
        int bidx = (iq - ik + WH - 1) * (2 * WW - 1) + (jq - jk + WW - 1);
        pm[item] = acc * scale + btab[bidx * NHEAD + head];
    }
    __syncthreads();

    if (tid < NHEAD * NTOK) {
        float* row = pm + tid * NTOK;
        float m = row[0];
        #pragma unroll
        for (int k = 1; k < NTOK; ++k) m = fmaxf(m, row[k]);
        float e[NTOK];
        float s = 0.f;
        #pragma unroll
        for (int k = 0; k < NTOK; ++k) { e[k] = __expf(row[k] - m); s += e[k]; }
        float inv = 1.0f / s;
        #pragma unroll
        for (int k = 0; k < NTOK; ++k) row[k] = e[k] * inv;
    }
    __syncthreads();

    int head = tid >> 5;
    float hv[NTOK];
    #pragma unroll
    for (int k = 0; k < NTOK; ++k) hv[k] = hs[k][tid];
    #pragma unroll
    for (int q = 0; q < NTOK; ++q) {
        const float* pr = pm + (head * NTOK + q) * NTOK;
        float acc = 0.f;
        #pragma unroll
        for (int k = 0; k < NTOK; ++k) acc += pr[k] * hv[k];
        float o = xs[q][tid] + acc;
        long l = base + (q >> 1) * WPAT + (q & 1);
        x1[l * DIM + tid] = o;
    }
}

// ---------------- kernel 2: LN2 + MLP (bf16 MFMA) + residual, in-place on d_out -----
__global__ __launch_bounds__(256, 2) void mlp_kernel(
    float* __restrict__ xio,
    const float* __restrict__ g2, const float* __restrict__ b2,
    const unsigned short* __restrict__ wtf,
    const float* __restrict__ mb1, const float* __restrict__ mb2) {
    __shared__ unsigned short As[64][DIM + 8];

    int m0 = blockIdx.x * 64;
    int tid = threadIdx.x;
    int lane = tid & 63;
    int wave = tid >> 6;
    int lr = lane & 15;   // row/col within 16
    int lk = lane >> 4;   // 0..3 (k-group / acc row group)
    int n0 = wave * 64;

    // per-wave fragment bases in prearranged weight buffer (shorts)
    const unsigned short* w1base = wtf + (size_t)wave * 16384 + (size_t)lane * 8;
    const unsigned short* w2base = wtf + 65536 + (size_t)wave * 16384 + (size_t)lane * 8;

    // ---- LN2: bulk ILP loads (4 threads/row, 16 independent float4 each)
    int r = tid >> 2;          // 0..63
    int q = tid & 3;           // 0..3
    const float4* rowp = (const float4*)(xio + (long)(m0 + r) * DIM);
    float4 v[16];
    #pragma unroll
    for (int i = 0; i < 16; ++i) v[i] = rowp[q + 4 * i];

    // issue GEMM1 weight burst (32 coalesced dwordx4, no deps) to overlap with LN math
    bh8 wf[4][8];
    #pragma unroll
    for (int ni = 0; ni < 4; ++ni)
        #pragma unroll
        for (int ko = 0; ko < 8; ++ko)
            wf[ni][ko] = *(const bh8*)(w1base + (size_t)(ni * 8 + ko) * 512);

    float bias1v[4];
    #pragma unroll
    for (int ni = 0; ni < 4; ++ni) bias1v[ni] = mb1[n0 + ni * 16 + lr];

    {
        float s = 0.f, sq = 0.f;
        #pragma unroll
        for (int i = 0; i < 16; ++i) {
            s += v[i].x + v[i].y + v[i].z + v[i].w;
            sq += v[i].x * v[i].x + v[i].y * v[i].y + v[i].z * v[i].z + v[i].w * v[i].w;
        }
        s += __shfl_xor(s, 1);  s += __shfl_xor(s, 2);
        sq += __shfl_xor(sq, 1); sq += __shfl_xor(sq, 2);
        float mean = s * (1.0f / DIM);
        float var = sq * (1.0f / DIM) - mean * mean;
        float rstd = rsqrtf(var + EPS);

        const float4* g4p = (const float4*)g2;
        const float4* b4p = (const float4*)b2;
        #pragma unroll
        for (int i = 0; i < 16; ++i) {
            int c4 = q + 4 * i;
            float4 gg = g4p[c4];
            float4 bb = b4p[c4];
            sh4 h;
            h.x = (short)f2bf((v[i].x - mean) * rstd * gg.x + bb.x);
            h.y = (short)f2bf((v[i].y - mean) * rstd * gg.y + bb.y);
            h.z = (short)f2bf((v[i].z - mean) * rstd * gg.z + bb.z);
            h.w = (short)f2bf((v[i].w - mean) * rstd * gg.w + bb.w);
            *(sh4*)&As[r][c4 * 4] = h;
        }
    }
    __syncthreads();

    const fx4 zero = {0.f, 0.f, 0.f, 0.f};

    // ---- GEMM1: pure LDS + register-resident weights
    fx4 acc[4][4];
    #pragma unroll
    for (int mi = 0; mi < 4; ++mi)
        #pragma unroll
        for (int ni = 0; ni < 4; ++ni) acc[mi][ni] = zero;

    #pragma unroll
    for (int ko = 0; ko < 8; ++ko) {
        bh8 a[4];
        #pragma unroll
        for (int mi = 0; mi < 4; ++mi)
            a[mi] = *(const bh8*)&As[mi * 16 + lr][ko * 32 + lk * 8];
        #pragma unroll
        for (int mi = 0; mi < 4; ++mi)
            #pragma unroll
            for (int ni = 0; ni < 4; ++ni)
                acc[mi][ni] = __builtin_amdgcn_mfma_f32_16x16x32_bf16(a[mi], wf[ni][ko], acc[mi][ni], 0, 0, 0);
    }
    __syncthreads();

    // issue GEMM2 weight burst now; latency hides under gelu VALU work
    #pragma unroll
    for (int ni = 0; ni < 4; ++ni)
        #pragma unroll
        for (int ko = 0; ko < 8; ++ko)
            wf[ni][ko] = *(const bh8*)(w2base + (size_t)(ni * 8 + ko) * 512);

    float bias2v[4];
    #pragma unroll
    for (int ni = 0; ni < 4; ++ni) bias2v[ni] = mb2[n0 + ni * 16 + lr];

    // ---- bias1 + gelu (tanh form: x*sigmoid(2t)) -> bf16 back into As
    #pragma unroll
    for (int mi = 0; mi < 4; ++mi)
        #pragma unroll
        for (int ni = 0; ni < 4; ++ni)
            #pragma unroll
            for (int rr = 0; rr < 4; ++rr) {
                float vv = acc[mi][ni][rr] + bias1v[ni];
                float t = 0.7978845608028654f * (vv + 0.044715f * vv * vv * vv);
                float ge = vv / (1.0f + __expf(-2.0f * t));
                As[mi * 16 + lk * 4 + rr][n0 + ni * 16 + lr] = f2bf(ge);
            }
    __syncthreads();

    // ---- GEMM2
    fx4 acc2[4][4];
    #pragma unroll
    for (int mi = 0; mi < 4; ++mi)
        #pragma unroll
        for (int ni = 0; ni < 4; ++ni) acc2[mi][ni] = zero;

    #pragma unroll
    for (int ko = 0; ko < 8; ++ko) {
        bh8 a[4];
        #pragma unroll
        for (int mi = 0; mi < 4; ++mi)
            a[mi] = *(const bh8*)&As[mi * 16 + lr][ko * 32 + lk * 8];
        #pragma unroll
        for (int mi = 0; mi < 4; ++mi)
            #pragma unroll
            for (int ni = 0; ni < 4; ++ni)
                acc2[mi][ni] = __builtin_amdgcn_mfma_f32_16x16x32_bf16(a[mi], wf[ni][ko], acc2[mi][ni], 0, 0, 0);
    }

    // ---- bias2 + residual, in-place store
    #pragma unroll
    for (int mi = 0; mi < 4; ++mi)
        #pragma unroll
        for (int ni = 0; ni < 4; ++ni)
            #pragma unroll
            for (int rr = 0; rr < 4; ++rr) {
                long row = m0 + mi * 16 + lk * 4 + rr;
                int col = n0 + ni * 16 + lr;
                long idx = row * DIM + col;
                xio[idx] = xio[idx] + acc2[mi][ni][rr] + bias2v[ni];
            }
}

extern "C" void kernel_launch(void* const* d_in, const int* in_sizes, int n_in,
                              void* d_out, int out_size, void* d_ws, size_t ws_size,
                              hipStream_t stream) {
    const float* x    = (const float*)d_in[0];
    const float* g1   = (const float*)d_in[1];
    const float* b1   = (const float*)d_in[2];
    const float* btab = (const float*)d_in[3];
    const float* g2   = (const float*)d_in[6];
    const float* b2   = (const float*)d_in[7];
    const float* w1   = (const float*)d_in[8];
    const float* mb1  = (const float*)d_in[9];
    const float* w2   = (const float*)d_in[10];
    const float* mb2  = (const float*)d_in[11];
    float* out = (float*)d_out;
    unsigned short* wtf = (unsigned short*)d_ws;

    prep_kernel<<<64, 256, 0, stream>>>(w1, w2, wtf);
    attn_kernel<<<16384, 256, 0, stream>>>(x, g1, b1, btab, out);
    mlp_kernel<<<2560, 256, 0, stream>>>(out, g2, b2, wtf, mb1, mb2);
}